// Round 4
// baseline (92.079 us; speedup 1.0000x reference)
//
#include <hip/hip_runtime.h>
#include <math.h>

typedef unsigned short u16;
typedef unsigned int   u32;

using bf16x8 = __attribute__((ext_vector_type(8))) short;
using f32x4  = __attribute__((ext_vector_type(4))) float;

#define NB   64      // batch
#define NE   8       // experts
#define DIN  320
#define NP   196     // real patches per image
#define MPAD 256     // padded row stride per image (A buffer)
#define CK   768     // inner dim (C*P*P)
#define CN   768     // out features

#define BM 128
#define BN 128
#define BK 32        // LDS row = 64 bytes = 4 chunks of 16B
#define NKT (CK / BK)   // 24

#define WCONV_BLOCKS 2304   // 8*768*768 / (8*256)
#define PATCH_BLOCKS 4704   // 64*196*96 / 256

__device__ __forceinline__ u16 f2bf(float f) {
    u32 u = __builtin_bit_cast(u32, f);
    u += 0x7fffu + ((u >> 16) & 1u);
    return (u16)(u >> 16);
}

__device__ __forceinline__ void gload16(const void* g, void* l) {
    __builtin_amdgcn_global_load_lds(
        (const __attribute__((address_space(1))) void*)g,
        (__attribute__((address_space(3))) void*)l, 16, 0, 0);
}

// ---------------- fused copy (no big LDS) + gate on block 0 (4.4 KB LDS) ----------------
__global__ __launch_bounds__(256) void copy_kernel(
    const float* __restrict__ x,
    const float* __restrict__ g,
    const float* __restrict__ noise,
    const float* __restrict__ w_gate,
    const float* __restrict__ w_noise,
    const float* __restrict__ w_exp,
    int* __restrict__ eid,
    float* __restrict__ loss_out,
    u16* __restrict__ patches,
    u16* __restrict__ wb)
{
    __shared__ float sNy[NB][NE];      // 2 KB
    __shared__ float sProb[NB][NE];    // 2 KB
    __shared__ int   sTop[NB];         // 256 B
    __shared__ float sImp[NE], sLoad[NE];

    int bid = blockIdx.x;
    const int t = threadIdx.x;

    if (bid == 0) {
        // ---- gating + loss: 256 threads x 2 (b,e) pairs; w read direct
        // (per-wave: 8 e-lanes x 8 b-groups -> one 32B broadcast line per i) ----
        float cls[2], sds[2], nys[2];
        #pragma unroll
        for (int pp = 0; pp < 2; ++pp) {
            int p = t + pp * 256;
            int b = p >> 3, e = p & 7;
            float cl = 0.f, nz = 0.f;
            const float* gr = g + b * DIN;
            #pragma unroll 4
            for (int i = 0; i < DIN; ++i) {
                float gv = gr[i];
                cl = fmaf(gv, w_gate[i * NE + e], cl);
                nz = fmaf(gv, w_noise[i * NE + e], nz);
            }
            // jax.nn.softplus == max(x,0)+log1p(exp(-|x|))
            float sd = fmaxf(nz, 0.f) + log1pf(expf(-fabsf(nz))) + 0.01f;
            float ny = fmaf(noise[p], sd, cl);
            sNy[b][e] = ny;
            cls[pp] = cl; sds[pp] = sd; nys[pp] = ny;
        }
        __syncthreads();
        #pragma unroll
        for (int pp = 0; pp < 2; ++pp) {
            int p = t + pp * 256;
            int b = p >> 3, e = p & 7;
            float v1 = -1e30f, v2 = -1e30f; int i1 = 0;
            #pragma unroll
            for (int k2 = 0; k2 < NE; ++k2) {
                float v = sNy[b][k2];
                if (v > v1) { v2 = v1; v1 = v; i1 = k2; }
                else if (v > v2) { v2 = v; }
            }
            if (e == 0) { sTop[b] = i1; eid[b] = i1; }
            // is_in: noisy > 2nd-largest (thr_in=v2); else threshold = largest (v1)
            float thr = (nys[pp] > v2) ? v2 : v1;
            float z = (cls[pp] - thr) / sds[pp];
            sProb[b][e] = 0.5f * (1.0f + erff(z * 0.7071067811865476f));
        }
        __syncthreads();
        if (t < NE) {
            float imp = 0.f, ld = 0.f;
            for (int i = 0; i < NB; ++i) {
                imp += (sTop[i] == t) ? 1.0f : 0.0f;
                ld  += sProb[i][t];
            }
            sImp[t] = imp; sLoad[t] = ld;
        }
        __syncthreads();
        if (t == 0) {
            float mi = 0.f, ml = 0.f;
            for (int k2 = 0; k2 < NE; ++k2) { mi += sImp[k2]; ml += sLoad[k2]; }
            mi *= (1.0f / NE); ml *= (1.0f / NE);
            float vi = 0.f, vl = 0.f;
            for (int k2 = 0; k2 < NE; ++k2) {
                float d1 = sImp[k2] - mi;  vi += d1 * d1;
                float d2 = sLoad[k2] - ml; vl += d2 * d2;
            }
            vi *= (1.0f / (NE - 1)); vl *= (1.0f / (NE - 1));  // ddof=1
            loss_out[0] = (vi / (mi * mi + 1e-10f) + vl / (ml * ml + 1e-10f)) * 0.01f;
        }
        return;
    }
    bid -= 1;

    if (bid < WCONV_BLOCKS) {
        // ---- w_exp fp32 -> bf16 ----
        int idx = bid * 256 + t;
        const float* src = w_exp + (size_t)idx * 8;
        float4 f0 = *reinterpret_cast<const float4*>(src);
        float4 f1 = *reinterpret_cast<const float4*>(src + 4);
        uint4 o;
        o.x = (u32)f2bf(f0.x) | ((u32)f2bf(f0.y) << 16);
        o.y = (u32)f2bf(f0.z) | ((u32)f2bf(f0.w) << 16);
        o.z = (u32)f2bf(f1.x) | ((u32)f2bf(f1.y) << 16);
        o.w = (u32)f2bf(f1.z) | ((u32)f2bf(f1.w) << 16);
        *reinterpret_cast<uint4*>(wb + (size_t)idx * 8) = o;
        return;
    }
    bid -= WCONV_BLOCKS;

    // ---- patchify + bf16 (real rows only; pad rows [196,256) never written) ----
    int idx = bid * 256 + t;
    int i8   = idx % 96;
    int rest = idx / 96;
    int p    = rest % NP;
    int b    = rest / NP;
    u16* dst = patches + ((size_t)(b * MPAD + p)) * CK + i8 * 8;
    int gh = p / 14, gw = p % 14;
    int i0  = i8 * 8;
    int c   = i0 >> 8;
    int rem = i0 & 255;
    int ph  = rem >> 4;
    int pw0 = rem & 15;
    const float* src = x + (((size_t)(b * 3 + c) * 224 + gh * 16 + ph) * 224 + gw * 16 + pw0);
    float4 f0 = *reinterpret_cast<const float4*>(src);
    float4 f1 = *reinterpret_cast<const float4*>(src + 4);
    uint4 o;
    o.x = (u32)f2bf(f0.x) | ((u32)f2bf(f0.y) << 16);
    o.y = (u32)f2bf(f0.z) | ((u32)f2bf(f0.w) << 16);
    o.z = (u32)f2bf(f1.x) | ((u32)f2bf(f1.y) << 16);
    o.w = (u32)f2bf(f1.z) | ((u32)f2bf(f1.w) << 16);
    *reinterpret_cast<uint4*>(dst) = o;
}

// ---------------- expert-selected batched GEMM, 2-phase dbuf + counted vmcnt ----------------
// UNCHANGED from round 3 (measured ~18 us): grid 768 blocks -> (b, m-tile,
// n-tile); 4 waves, wave tile 64x64; global_load_lds w/ both-sides chunk
// swizzle; double-buffered LDS; prefetch issued before compute; vmcnt(4).
__global__ __launch_bounds__(256) void gemm_kernel(
    const u16* __restrict__ patches,
    const u16* __restrict__ wb,
    const float* __restrict__ b_exp,
    const int* __restrict__ eid,
    float* __restrict__ out)
{
    __shared__ char smem[2][16384];   // per buffer: A 8KB | B 8KB

    const int id = blockIdx.x;
    // bijective XCD swizzle: 96 consecutive virtual blocks (=8 images) per XCD
    const int v  = (id & 7) * 96 + (id >> 3);
    const int b  = v / 12;
    const int rr = v % 12;
    const int m0 = (rr / 6) * BM;
    const int n0 = (rr % 6) * BN;
    const int e  = eid[b];

    const int t  = threadIdx.x;
    const int l  = t & 63;
    const int w  = t >> 6;
    const int wm = w >> 1;
    const int wn = w & 1;

    // staging: wave w part j -> LDS bytes w*2048 + j*1024 + l*16
    // -> row r = w*32 + j*16 + (l>>2), chunk c' = l&3
    // pre-swizzled global chunk cg = c' ^ ((r>>2)&3) = (l&3) ^ (l>>4)
    const int rs = (w << 5) + (l >> 2);
    const u32 cg = (u32)((l & 3) ^ (l >> 4));
    const u16* aSrc = patches + ((size_t)(b * MPAD) + m0 + rs) * CK + cg * 8;
    const u16* bSrc = wb + (size_t)e * CK * CN + (size_t)(n0 + rs) * CK + cg * 8;
    const u32 lOff = (u32)(w * 2048);
    char* smem0 = &smem[0][0];

    // fragment read offsets (same swizzle), within A / B region
    u32 aOff[4], bOff[4];
    #pragma unroll
    for (int fm = 0; fm < 4; ++fm) {
        int row = wm * 64 + fm * 16 + (l & 15);
        u32 c = (u32)(l >> 4) ^ (u32)((row >> 2) & 3);
        aOff[fm] = (u32)row * 64 + c * 16;
    }
    #pragma unroll
    for (int fn = 0; fn < 4; ++fn) {
        int row = wn * 64 + fn * 16 + (l & 15);
        u32 c = (u32)(l >> 4) ^ (u32)((row >> 2) & 3);
        bOff[fn] = (u32)row * 64 + c * 16;
    }

    f32x4 acc[4][4];
    #pragma unroll
    for (int fm = 0; fm < 4; ++fm)
        #pragma unroll
        for (int fn = 0; fn < 4; ++fn)
            acc[fm][fn] = (f32x4){0.f, 0.f, 0.f, 0.f};

    // prologue: stage tile 0 into buf 0
    gload16(aSrc,           smem0 + lOff);
    gload16(aSrc + 16 * CK, smem0 + lOff + 1024);
    gload16(bSrc,           smem0 + 8192 + lOff);
    gload16(bSrc + 16 * CK, smem0 + 8192 + lOff + 1024);
    aSrc += BK; bSrc += BK;

    for (int kt = 0; kt < NKT - 1; ++kt) {
        // issue prefetch of tile kt+1 into the other buffer
        char* sn = smem0 + (u32)(((kt + 1) & 1) * 16384);
        gload16(aSrc,           sn + lOff);
        gload16(aSrc + 16 * CK, sn + lOff + 1024);
        gload16(bSrc,           sn + 8192 + lOff);
        gload16(bSrc + 16 * CK, sn + 8192 + lOff + 1024);
        aSrc += BK; bSrc += BK;

        // wait only for tile kt's 4 loads (prefetch stays in flight)
        asm volatile("s_waitcnt vmcnt(4)" ::: "memory");
        __builtin_amdgcn_s_barrier();

        char* sc = smem0 + (u32)((kt & 1) * 16384);
        bf16x8 af[4], bfr[4];
        #pragma unroll
        for (int fm = 0; fm < 4; ++fm)
            af[fm] = *reinterpret_cast<const bf16x8*>(sc + aOff[fm]);
        #pragma unroll
        for (int fn = 0; fn < 4; ++fn)
            bfr[fn] = *reinterpret_cast<const bf16x8*>(sc + 8192 + bOff[fn]);

        #pragma unroll
        for (int fm = 0; fm < 4; ++fm)
            #pragma unroll
            for (int fn = 0; fn < 4; ++fn)
                acc[fm][fn] = __builtin_amdgcn_mfma_f32_16x16x32_bf16(
                    af[fm], bfr[fn], acc[fm][fn], 0, 0, 0);

        __builtin_amdgcn_s_barrier();   // reads done before buffer reuse
    }

    // epilogue tile NKT-1 (in buf 1)
    asm volatile("s_waitcnt vmcnt(0)" ::: "memory");
    __builtin_amdgcn_s_barrier();
    {
        char* sc = smem0 + (u32)(((NKT - 1) & 1) * 16384);
        bf16x8 af[4], bfr[4];
        #pragma unroll
        for (int fm = 0; fm < 4; ++fm)
            af[fm] = *reinterpret_cast<const bf16x8*>(sc + aOff[fm]);
        #pragma unroll
        for (int fn = 0; fn < 4; ++fn)
            bfr[fn] = *reinterpret_cast<const bf16x8*>(sc + 8192 + bOff[fn]);
        #pragma unroll
        for (int fm = 0; fm < 4; ++fm)
            #pragma unroll
            for (int fn = 0; fn < 4; ++fn)
                acc[fm][fn] = __builtin_amdgcn_mfma_f32_16x16x32_bf16(
                    af[fm], bfr[fn], acc[fm][fn], 0, 0, 0);
    }

    // ---- store: bias + eps-replace, rows < 196 only ----
    const int r4 = (l >> 4) * 4;
    #pragma unroll
    for (int fm = 0; fm < 4; ++fm) {
        int mb = m0 + wm * 64 + fm * 16 + r4;
        #pragma unroll
        for (int fn = 0; fn < 4; ++fn) {
            int col = n0 + wn * 64 + fn * 16 + (l & 15);
            float bias = b_exp[e * CN + col];
            #pragma unroll
            for (int q = 0; q < 4; ++q) {
                int mrow = mb + q;
                if (mrow < NP) {
                    float vv = acc[fm][fn][q] + bias;
                    if (vv == 0.0f) vv = 2.220446049250313e-16f;
                    out[((size_t)b * NP + mrow) * CN + col] = vv;
                }
            }
        }
    }
}

extern "C" void kernel_launch(void* const* d_in, const int* in_sizes, int n_in,
                              void* d_out, int out_size, void* d_ws, size_t ws_size,
                              hipStream_t stream) {
    const float* x       = (const float*)d_in[0];
    const float* g       = (const float*)d_in[1];
    const float* noise   = (const float*)d_in[2];
    const float* w_gate  = (const float*)d_in[3];
    const float* w_noise = (const float*)d_in[4];
    const float* w_exp   = (const float*)d_in[5];
    const float* b_exp   = (const float*)d_in[6];
    float* out = (float*)d_out;

    char* ws = (char*)d_ws;
    int* eid      = (int*)ws;                                        // 256 B
    u16* patches  = (u16*)(ws + 1024);                               // 64*256*768*2
    u16* wbf      = (u16*)(ws + 1024 + (size_t)NB * MPAD * CK * 2);  // 8*768*768*2

    hipLaunchKernelGGL(copy_kernel, dim3(1 + WCONV_BLOCKS + PATCH_BLOCKS), dim3(256), 0, stream,
                       x, g, noise, w_gate, w_noise, w_exp,
                       eid, out + (size_t)NB * NP * CN, patches, wbf);
    hipLaunchKernelGGL(gemm_kernel, dim3(CN / BN * MPAD / BM * NB), dim3(256), 0, stream,
                       patches, wbf, b_exp, eid, out);
}

// Round 5
// 69.169 us; speedup vs baseline: 1.3312x; 1.3312x over previous
//
#include <hip/hip_runtime.h>
#include <math.h>

typedef unsigned short u16;
typedef unsigned int   u32;

using bf16x8 = __attribute__((ext_vector_type(8))) short;
using f32x4  = __attribute__((ext_vector_type(4))) float;

#define NB   64      // batch
#define NE   8       // experts
#define DIN  320
#define NP   196     // real patches per image
#define MPAD 256     // padded row stride per image (A buffer)
#define CK   768     // inner dim (C*P*P)
#define CN   768     // out features

#define BM 128
#define BN 128
#define BK 32        // LDS row = 64 bytes = 4 chunks of 16B
#define NKT (CK / BK)   // 24

__device__ __forceinline__ u16 f2bf(float f) {
    u32 u = __builtin_bit_cast(u32, f);
    u += 0x7fffu + ((u >> 16) & 1u);
    return (u16)(u >> 16);
}

__device__ __forceinline__ void gload16(const void* g, void* l) {
    __builtin_amdgcn_global_load_lds(
        (const __attribute__((address_space(1))) void*)g,
        (__attribute__((address_space(3))) void*)l, 16, 0, 0);
}

// ---------------- gate stage 1: logits (8 blocks x 8 images each) ----------------
// thread = (pair, q): pair=(b_local,e), q in [0,4) sums 80 of the 320 dims.
__global__ __launch_bounds__(256) void gate1_kernel(
    const float* __restrict__ g,
    const float* __restrict__ noise,
    const float* __restrict__ w_gate,
    const float* __restrict__ w_noise,
    float* __restrict__ gCl, float* __restrict__ gSd, float* __restrict__ gNy)
{
    __shared__ float sW[DIN][NE];    // 10 KB
    __shared__ float sWn[DIN][NE];   // 10 KB
    __shared__ float sG[8][DIN];     // 10 KB
    const int t  = threadIdx.x;
    const int b0 = blockIdx.x * 8;
    for (int i = t; i < DIN * NE; i += 256) {
        sW[i >> 3][i & 7]  = w_gate[i];
        sWn[i >> 3][i & 7] = w_noise[i];
        sG[i / DIN][i % DIN] = g[b0 * DIN + i];
    }
    __syncthreads();
    const int pair = t >> 2, q = t & 3;
    const int bl = pair >> 3, e = pair & 7;
    float cl = 0.f, nz = 0.f;
    const int i0 = q * 80;
    #pragma unroll 4
    for (int j = 0; j < 80; ++j) {
        float gv = sG[bl][i0 + j];
        cl = fmaf(gv, sW[i0 + j][e], cl);
        nz = fmaf(gv, sWn[i0 + j][e], nz);
    }
    cl += __shfl_xor(cl, 1); cl += __shfl_xor(cl, 2);
    nz += __shfl_xor(nz, 1); nz += __shfl_xor(nz, 2);
    if (q == 0) {
        int p = (b0 + bl) * NE + e;
        // jax.nn.softplus == max(x,0)+log1p(exp(-|x|))
        float sd = fmaxf(nz, 0.f) + log1pf(expf(-fabsf(nz))) + 0.01f;
        gCl[p] = cl; gSd[p] = sd;
        gNy[p] = fmaf(noise[p], sd, cl);
    }
}

// ---------------- gate stage 2: top-2, probs, loss, eid (1 block) ----------------
__global__ __launch_bounds__(512) void gate2_kernel(
    const float* __restrict__ gCl,
    const float* __restrict__ gSd,
    const float* __restrict__ gNy,
    int* __restrict__ eid,
    float* __restrict__ loss_out)
{
    __shared__ float sNy[NB][NE];
    __shared__ float sProb[NB][NE];
    __shared__ int   sTop[NB];
    __shared__ float sImp[NE], sLoad[NE];
    const int t = threadIdx.x;            // 512 = one (b,e) pair each
    const int b = t >> 3, e = t & 7;
    float cl = gCl[t], sd = gSd[t], ny = gNy[t];
    sNy[b][e] = ny;
    __syncthreads();
    float v1 = -1e30f, v2 = -1e30f; int i1 = 0;
    #pragma unroll
    for (int k2 = 0; k2 < NE; ++k2) {
        float v = sNy[b][k2];
        if (v > v1) { v2 = v1; v1 = v; i1 = k2; }
        else if (v > v2) { v2 = v; }
    }
    if (e == 0) { sTop[b] = i1; eid[b] = i1; }
    // is_in: noisy > 2nd-largest (thr_in=v2); else threshold = largest (v1)
    float thr = (ny > v2) ? v2 : v1;
    float z = (cl - thr) / sd;
    sProb[b][e] = 0.5f * (1.0f + erff(z * 0.7071067811865476f));
    __syncthreads();
    if (t < NE) {
        float imp = 0.f, ld = 0.f;
        for (int i = 0; i < NB; ++i) {
            imp += (sTop[i] == t) ? 1.0f : 0.0f;
            ld  += sProb[i][t];
        }
        sImp[t] = imp; sLoad[t] = ld;
    }
    __syncthreads();
    if (t == 0) {
        float mi = 0.f, ml = 0.f;
        for (int k2 = 0; k2 < NE; ++k2) { mi += sImp[k2]; ml += sLoad[k2]; }
        mi *= (1.0f / NE); ml *= (1.0f / NE);
        float vi = 0.f, vl = 0.f;
        for (int k2 = 0; k2 < NE; ++k2) {
            float d1 = sImp[k2] - mi;  vi += d1 * d1;
            float d2 = sLoad[k2] - ml; vl += d2 * d2;
        }
        vi *= (1.0f / (NE - 1)); vl *= (1.0f / (NE - 1));  // ddof=1
        loss_out[0] = (vi / (mi * mi + 1e-10f) + vl / (ml * ml + 1e-10f)) * 0.01f;
    }
}

// ---------------- w_exp fp32 -> bf16 (separate dispatch, round-2-validated) ----------------
__global__ void wconv_kernel(const float* __restrict__ w, u16* __restrict__ wb)
{
    int idx = blockIdx.x * 256 + threadIdx.x;     // 8 elems per thread
    const float* src = w + (size_t)idx * 8;
    float4 f0 = *reinterpret_cast<const float4*>(src);
    float4 f1 = *reinterpret_cast<const float4*>(src + 4);
    uint4 o;
    o.x = (u32)f2bf(f0.x) | ((u32)f2bf(f0.y) << 16);
    o.y = (u32)f2bf(f0.z) | ((u32)f2bf(f0.w) << 16);
    o.z = (u32)f2bf(f1.x) | ((u32)f2bf(f1.y) << 16);
    o.w = (u32)f2bf(f1.z) | ((u32)f2bf(f1.w) << 16);
    *reinterpret_cast<uint4*>(wb + (size_t)idx * 8) = o;
}

// ---------------- patchify + bf16 (real rows only) ----------------
__global__ void patchify_kernel(const float* __restrict__ x, u16* __restrict__ patches)
{
    int idx = blockIdx.x * 256 + threadIdx.x;     // 64*196*96 threads
    int i8   = idx % 96;
    int rest = idx / 96;
    int p    = rest % NP;
    int b    = rest / NP;
    u16* dst = patches + ((size_t)(b * MPAD + p)) * CK + i8 * 8;
    int gh = p / 14, gw = p % 14;
    int i0  = i8 * 8;
    int c   = i0 >> 8;
    int rem = i0 & 255;
    int ph  = rem >> 4;
    int pw0 = rem & 15;
    const float* src = x + (((size_t)(b * 3 + c) * 224 + gh * 16 + ph) * 224 + gw * 16 + pw0);
    float4 f0 = *reinterpret_cast<const float4*>(src);
    float4 f1 = *reinterpret_cast<const float4*>(src + 4);
    uint4 o;
    o.x = (u32)f2bf(f0.x) | ((u32)f2bf(f0.y) << 16);
    o.y = (u32)f2bf(f0.z) | ((u32)f2bf(f0.w) << 16);
    o.z = (u32)f2bf(f1.x) | ((u32)f2bf(f1.y) << 16);
    o.w = (u32)f2bf(f1.z) | ((u32)f2bf(f1.w) << 16);
    *reinterpret_cast<uint4*>(dst) = o;
}

// ---------------- expert-selected batched GEMM, 2-phase dbuf + counted vmcnt ----------------
// UNCHANGED (measured fast): 768 blocks -> (b, m-tile, n-tile); 4 waves, wave
// tile 64x64; global_load_lds + both-sides chunk swizzle; dbuf LDS; prefetch
// before compute; s_waitcnt vmcnt(4).
__global__ __launch_bounds__(256) void gemm_kernel(
    const u16* __restrict__ patches,
    const u16* __restrict__ wb,
    const float* __restrict__ b_exp,
    const int* __restrict__ eid,
    float* __restrict__ out)
{
    __shared__ char smem[2][16384];   // per buffer: A 8KB | B 8KB

    const int id = blockIdx.x;
    // bijective XCD swizzle: 96 consecutive virtual blocks (=8 images) per XCD
    const int v  = (id & 7) * 96 + (id >> 3);
    const int b  = v / 12;
    const int rr = v % 12;
    const int m0 = (rr / 6) * BM;
    const int n0 = (rr % 6) * BN;
    const int e  = eid[b];

    const int t  = threadIdx.x;
    const int l  = t & 63;
    const int w  = t >> 6;
    const int wm = w >> 1;
    const int wn = w & 1;

    // staging: wave w part j -> LDS bytes w*2048 + j*1024 + l*16
    // -> row r = w*32 + j*16 + (l>>2), chunk c' = l&3
    // pre-swizzled global chunk cg = c' ^ ((r>>2)&3) = (l&3) ^ (l>>4)
    const int rs = (w << 5) + (l >> 2);
    const u32 cg = (u32)((l & 3) ^ (l >> 4));
    const u16* aSrc = patches + ((size_t)(b * MPAD) + m0 + rs) * CK + cg * 8;
    const u16* bSrc = wb + (size_t)e * CK * CN + (size_t)(n0 + rs) * CK + cg * 8;
    const u32 lOff = (u32)(w * 2048);
    char* smem0 = &smem[0][0];

    // fragment read offsets (same swizzle), within A / B region
    u32 aOff[4], bOff[4];
    #pragma unroll
    for (int fm = 0; fm < 4; ++fm) {
        int row = wm * 64 + fm * 16 + (l & 15);
        u32 c = (u32)(l >> 4) ^ (u32)((row >> 2) & 3);
        aOff[fm] = (u32)row * 64 + c * 16;
    }
    #pragma unroll
    for (int fn = 0; fn < 4; ++fn) {
        int row = wn * 64 + fn * 16 + (l & 15);
        u32 c = (u32)(l >> 4) ^ (u32)((row >> 2) & 3);
        bOff[fn] = (u32)row * 64 + c * 16;
    }

    f32x4 acc[4][4];
    #pragma unroll
    for (int fm = 0; fm < 4; ++fm)
        #pragma unroll
        for (int fn = 0; fn < 4; ++fn)
            acc[fm][fn] = (f32x4){0.f, 0.f, 0.f, 0.f};

    // prologue: stage tile 0 into buf 0
    gload16(aSrc,           smem0 + lOff);
    gload16(aSrc + 16 * CK, smem0 + lOff + 1024);
    gload16(bSrc,           smem0 + 8192 + lOff);
    gload16(bSrc + 16 * CK, smem0 + 8192 + lOff + 1024);
    aSrc += BK; bSrc += BK;

    for (int kt = 0; kt < NKT - 1; ++kt) {
        // issue prefetch of tile kt+1 into the other buffer
        char* sn = smem0 + (u32)(((kt + 1) & 1) * 16384);
        gload16(aSrc,           sn + lOff);
        gload16(aSrc + 16 * CK, sn + lOff + 1024);
        gload16(bSrc,           sn + 8192 + lOff);
        gload16(bSrc + 16 * CK, sn + 8192 + lOff + 1024);
        aSrc += BK; bSrc += BK;

        // wait only for tile kt's 4 loads (prefetch stays in flight)
        asm volatile("s_waitcnt vmcnt(4)" ::: "memory");
        __builtin_amdgcn_s_barrier();

        char* sc = smem0 + (u32)((kt & 1) * 16384);
        bf16x8 af[4], bfr[4];
        #pragma unroll
        for (int fm = 0; fm < 4; ++fm)
            af[fm] = *reinterpret_cast<const bf16x8*>(sc + aOff[fm]);
        #pragma unroll
        for (int fn = 0; fn < 4; ++fn)
            bfr[fn] = *reinterpret_cast<const bf16x8*>(sc + 8192 + bOff[fn]);

        #pragma unroll
        for (int fm = 0; fm < 4; ++fm)
            #pragma unroll
            for (int fn = 0; fn < 4; ++fn)
                acc[fm][fn] = __builtin_amdgcn_mfma_f32_16x16x32_bf16(
                    af[fm], bfr[fn], acc[fm][fn], 0, 0, 0);

        __builtin_amdgcn_s_barrier();   // reads done before buffer reuse
    }

    // epilogue tile NKT-1 (in buf 1)
    asm volatile("s_waitcnt vmcnt(0)" ::: "memory");
    __builtin_amdgcn_s_barrier();
    {
        char* sc = smem0 + (u32)(((NKT - 1) & 1) * 16384);
        bf16x8 af[4], bfr[4];
        #pragma unroll
        for (int fm = 0; fm < 4; ++fm)
            af[fm] = *reinterpret_cast<const bf16x8*>(sc + aOff[fm]);
        #pragma unroll
        for (int fn = 0; fn < 4; ++fn)
            bfr[fn] = *reinterpret_cast<const bf16x8*>(sc + 8192 + bOff[fn]);
        #pragma unroll
        for (int fm = 0; fm < 4; ++fm)
            #pragma unroll
            for (int fn = 0; fn < 4; ++fn)
                acc[fm][fn] = __builtin_amdgcn_mfma_f32_16x16x32_bf16(
                    af[fm], bfr[fn], acc[fm][fn], 0, 0, 0);
    }

    // ---- store: bias + eps-replace, rows < 196 only ----
    const int r4 = (l >> 4) * 4;
    #pragma unroll
    for (int fm = 0; fm < 4; ++fm) {
        int mb = m0 + wm * 64 + fm * 16 + r4;
        #pragma unroll
        for (int fn = 0; fn < 4; ++fn) {
            int col = n0 + wn * 64 + fn * 16 + (l & 15);
            float bias = b_exp[e * CN + col];
            #pragma unroll
            for (int q = 0; q < 4; ++q) {
                int mrow = mb + q;
                if (mrow < NP) {
                    float vv = acc[fm][fn][q] + bias;
                    if (vv == 0.0f) vv = 2.220446049250313e-16f;
                    out[((size_t)b * NP + mrow) * CN + col] = vv;
                }
            }
        }
    }
}

extern "C" void kernel_launch(void* const* d_in, const int* in_sizes, int n_in,
                              void* d_out, int out_size, void* d_ws, size_t ws_size,
                              hipStream_t stream) {
    const float* x       = (const float*)d_in[0];
    const float* g       = (const float*)d_in[1];
    const float* noise   = (const float*)d_in[2];
    const float* w_gate  = (const float*)d_in[3];
    const float* w_noise = (const float*)d_in[4];
    const float* w_exp   = (const float*)d_in[5];
    const float* b_exp   = (const float*)d_in[6];
    float* out = (float*)d_out;

    char* ws = (char*)d_ws;
    int*   eid     = (int*)ws;                                       // 256 B
    float* gCl     = (float*)(ws + 256);                             // 2 KB
    float* gSd     = (float*)(ws + 256 + 2048);                      // 2 KB
    float* gNy     = (float*)(ws + 256 + 4096);                      // 2 KB
    u16*   patches = (u16*)(ws + 8192);                              // 64*256*768*2
    u16*   wbf     = (u16*)(ws + 8192 + (size_t)NB * MPAD * CK * 2); // 8*768*768*2

    hipLaunchKernelGGL(gate1_kernel, dim3(8), dim3(256), 0, stream,
                       g, noise, w_gate, w_noise, gCl, gSd, gNy);
    hipLaunchKernelGGL(gate2_kernel, dim3(1), dim3(512), 0, stream,
                       gCl, gSd, gNy, eid, out + (size_t)NB * NP * CN);
    hipLaunchKernelGGL(wconv_kernel, dim3((NE * CN * CK / 8) / 256), dim3(256), 0, stream,
                       w_exp, wbf);
    hipLaunchKernelGGL(patchify_kernel, dim3((NB * NP * 96) / 256), dim3(256), 0, stream,
                       x, patches);
    hipLaunchKernelGGL(gemm_kernel, dim3(CN / BN * MPAD / BM * NB), dim3(256), 0, stream,
                       patches, wbf, b_exp, eid, out);
}

// Round 6
// 58.013 us; speedup vs baseline: 1.5872x; 1.1923x over previous
//
#include <hip/hip_runtime.h>
#include <math.h>

typedef unsigned short u16;
typedef unsigned int   u32;

using bf16x8 = __attribute__((ext_vector_type(8))) short;
using f32x4  = __attribute__((ext_vector_type(4))) float;

#define NB   64      // batch
#define NE   8       // experts
#define DIN  320
#define NP   196     // real patches per image
#define CK   768     // inner dim (C*P*P)
#define CN   768     // out features

#define BM 128
#define BN 128
#define BK 32        // LDS row = 64 B = 4 chunks of 16B
#define NKT (CK / BK)   // 24

#define WCONV_BLOCKS 2304   // 8*768*768 / (8*256)

__device__ __forceinline__ u16 f2bf(float f) {
    u32 u = __builtin_bit_cast(u32, f);
    u += 0x7fffu + ((u >> 16) & 1u);
    return (u16)(u >> 16);
}

// round-half-up f32->bf16 pair pack (ties differ from RNE only on exact .5 ulp)
__device__ __forceinline__ u32 pkbf(float a, float b) {
    u32 ua = (__builtin_bit_cast(u32, a) + 0x8000u) >> 16;
    u32 ub = (__builtin_bit_cast(u32, b) + 0x8000u) & 0xffff0000u;
    return ua | ub;
}

__device__ __forceinline__ void gload16(const void* g, void* l) {
    __builtin_amdgcn_global_load_lds(
        (const __attribute__((address_space(1))) void*)g,
        (__attribute__((address_space(3))) void*)l, 16, 0, 0);
}

// ---------------- prep1: gate1 (blocks 0..7) + wconv (rest) ----------------
__global__ __launch_bounds__(256) void prep1_kernel(
    const float* __restrict__ g,
    const float* __restrict__ noise,
    const float* __restrict__ w_gate,
    const float* __restrict__ w_noise,
    const float* __restrict__ w_exp,
    float* __restrict__ gCl, float* __restrict__ gSd, float* __restrict__ gNy,
    u16* __restrict__ wb)
{
    __shared__ float sW[DIN][NE + 1];    // +1 pad: breaks 8-way bank conflict
    __shared__ float sWn[DIN][NE + 1];
    const int t = threadIdx.x;
    int bid = blockIdx.x;

    if (bid < 8) {
        // ---- gate stage 1: 8 blocks x 8 images; thread=(pair,q), q sums 80 dims
        for (int i = t; i < DIN * NE; i += 256) {
            sW[i >> 3][i & 7]  = w_gate[i];
            sWn[i >> 3][i & 7] = w_noise[i];
        }
        __syncthreads();
        const int pair = t >> 2, q = t & 3;
        const int bl = pair >> 3, e = pair & 7;
        const int b = bid * 8 + bl;
        float cl = 0.f, nz = 0.f;
        const float* gr = g + b * DIN + q * 80;
        #pragma unroll 4
        for (int j = 0; j < 80; ++j) {
            float gv = gr[j];
            cl = fmaf(gv, sW[q * 80 + j][e], cl);
            nz = fmaf(gv, sWn[q * 80 + j][e], nz);
        }
        cl += __shfl_xor(cl, 1); cl += __shfl_xor(cl, 2);
        nz += __shfl_xor(nz, 1); nz += __shfl_xor(nz, 2);
        if (q == 0) {
            int p = b * NE + e;
            // jax.nn.softplus == max(x,0)+log1p(exp(-|x|))
            float sd = fmaxf(nz, 0.f) + log1pf(expf(-fabsf(nz))) + 0.01f;
            gCl[p] = cl; gSd[p] = sd;
            gNy[p] = fmaf(noise[p], sd, cl);
        }
        return;
    }
    bid -= 8;
    // ---- w_exp fp32 -> bf16 (8 elems/thread) ----
    int idx = bid * 256 + t;
    const float* src = w_exp + (size_t)idx * 8;
    float4 f0 = *reinterpret_cast<const float4*>(src);
    float4 f1 = *reinterpret_cast<const float4*>(src + 4);
    uint4 o;
    o.x = (u32)f2bf(f0.x) | ((u32)f2bf(f0.y) << 16);
    o.y = (u32)f2bf(f0.z) | ((u32)f2bf(f0.w) << 16);
    o.z = (u32)f2bf(f1.x) | ((u32)f2bf(f1.y) << 16);
    o.w = (u32)f2bf(f1.z) | ((u32)f2bf(f1.w) << 16);
    *reinterpret_cast<uint4*>(wb + (size_t)idx * 8) = o;
}

// ---------------- gate stage 2: top-2, probs, loss, eid (1 block) ----------------
__global__ __launch_bounds__(512) void gate2_kernel(
    const float* __restrict__ gCl,
    const float* __restrict__ gSd,
    const float* __restrict__ gNy,
    int* __restrict__ eid,
    float* __restrict__ loss_out)
{
    __shared__ float sNy[NB][NE];
    __shared__ float sProb[NB][NE];
    __shared__ int   sTop[NB];
    __shared__ float sImp[NE], sLoad[NE];
    const int t = threadIdx.x;            // 512 = one (b,e) pair each
    const int b = t >> 3, e = t & 7;
    float cl = gCl[t], sd = gSd[t], ny = gNy[t];
    sNy[b][e] = ny;
    __syncthreads();
    float v1 = -1e30f, v2 = -1e30f; int i1 = 0;
    #pragma unroll
    for (int k2 = 0; k2 < NE; ++k2) {
        float v = sNy[b][k2];
        if (v > v1) { v2 = v1; v1 = v; i1 = k2; }
        else if (v > v2) { v2 = v; }
    }
    if (e == 0) { sTop[b] = i1; eid[b] = i1; }
    // is_in: noisy > 2nd-largest (thr_in=v2); else threshold = largest (v1)
    float thr = (ny > v2) ? v2 : v1;
    float z = (cl - thr) / sd;
    sProb[b][e] = 0.5f * (1.0f + erff(z * 0.7071067811865476f));
    __syncthreads();
    if (t < NE) {
        float imp = 0.f, ld = 0.f;
        for (int i = 0; i < NB; ++i) {
            imp += (sTop[i] == t) ? 1.0f : 0.0f;
            ld  += sProb[i][t];
        }
        sImp[t] = imp; sLoad[t] = ld;
    }
    __syncthreads();
    if (t == 0) {
        float mi = 0.f, ml = 0.f;
        for (int k2 = 0; k2 < NE; ++k2) { mi += sImp[k2]; ml += sLoad[k2]; }
        mi *= (1.0f / NE); ml *= (1.0f / NE);
        float vi = 0.f, vl = 0.f;
        for (int k2 = 0; k2 < NE; ++k2) {
            float d1 = sImp[k2] - mi;  vi += d1 * d1;
            float d2 = sLoad[k2] - ml; vl += d2 * d2;
        }
        vi *= (1.0f / (NE - 1)); vl *= (1.0f / (NE - 1));  // ddof=1
        loss_out[0] = (vi / (mi * mi + 1e-10f) + vl / (ml * ml + 1e-10f)) * 0.01f;
    }
}

// ---------------- fused patchify + expert GEMM ----------------
// 768 blocks -> (image b, m-tile 0/1, n-tile 0..5); 512 thr = 8 waves (4x2),
// wave tile 32x64 (2x4 frags of 16x16x32). A staged from x directly:
// global f32 -> regs -> bf16 -> swizzled ds_write (T14 issue-early/write-late).
// B staged via global_load_lds, dbuf, counted vmcnt(3) (prefetch never drained).
__global__ __launch_bounds__(512) void gemm_kernel(
    const float* __restrict__ x,
    const u16* __restrict__ wb,
    const float* __restrict__ b_exp,
    const int* __restrict__ eid,
    float* __restrict__ out)
{
    __shared__ char smem[2][16384];   // per buffer: A 8KB | B 8KB

    const int id = blockIdx.x;
    // bijective XCD swizzle: 96 consecutive virtual blocks (=8 images) per XCD
    const int v  = (id & 7) * 96 + (id >> 3);
    const int b  = v / 12;
    const int rr = v % 12;
    const int m0 = (rr / 6) * BM;
    const int n0 = (rr % 6) * BN;
    const int e  = eid[b];

    const int t  = threadIdx.x;   // 0..511
    const int l  = t & 63;
    const int w  = t >> 6;        // 0..7
    const int wm = w >> 1;        // 0..3 -> 32-row slice
    const int wn = w & 1;         // 0..1 -> 64-col slice

    // ---- B staging (gload_lds): wave w stages rows [w*16, w*16+16) ----
    // LDS byte = 8192 + w*1024 + l*16 -> row = w*16+(l>>2), chunk c' = l&3
    // pre-swizzled global chunk cg = c' ^ ((row>>2)&3) = (l&3)^(l>>4)
    const u32 cg = (u32)((l & 3) ^ (l >> 4));
    const u16* bS = wb + (size_t)e * (CK * CN)
                  + (size_t)(n0 + (w << 4) + (l >> 2)) * CK + cg * 8;
    const u32 bLds = 8192u + ((u32)w << 10) + ((u32)l << 4);

    // ---- A staging (reg->LDS): thread t handles row t>>2, 8 floats ----
    // k-chunk of 32 = channel c=kt>>3, two pixel rows ph=(kt&7)*2+seg (16 px each)
    // thread covers floats [ (t&1)*8, +8 ) of seg=(t&3)>>1
    const int arow = t >> 2;
    int p = m0 + arow; if (p > NP - 1) p = NP - 1;   // clamp pad rows (never stored)
    const int gh = p / 14, gw = p % 14;
    const int seg = (t & 3) >> 1, pw0 = (t & 1) * 8;
    const float* xb = x + (size_t)b * 150528 + (gh * 16 + seg) * 224 + gw * 16 + pw0;
    // dest: row*64 + swizzled chunk (t&3), 16B per thread
    const u32 wA = (u32)(arow * 64 + (((t & 3) ^ ((arow >> 2) & 3)) << 4));

    // ---- fragment read offsets (same chunk swizzle) ----
    u32 aOff[2], bOff[4];
    #pragma unroll
    for (int fm = 0; fm < 2; ++fm) {
        int row = wm * 32 + fm * 16 + (l & 15);
        aOff[fm] = (u32)(row * 64) + (((u32)(l >> 4) ^ (u32)((row >> 2) & 3)) << 4);
    }
    #pragma unroll
    for (int fn = 0; fn < 4; ++fn) {
        int row = wn * 64 + fn * 16 + (l & 15);
        bOff[fn] = 8192u + (u32)(row * 64) + (((u32)(l >> 4) ^ (u32)((row >> 2) & 3)) << 4);
    }

    f32x4 acc[2][4];
    #pragma unroll
    for (int fm = 0; fm < 2; ++fm)
        #pragma unroll
        for (int fn = 0; fn < 4; ++fn)
            acc[fm][fn] = (f32x4){0.f, 0.f, 0.f, 0.f};

    char* smem0 = &smem[0][0];

    // ---- prologue: tile 0 into buf 0 ----
    {
        float4 ra0 = *reinterpret_cast<const float4*>(xb);
        float4 ra1 = *reinterpret_cast<const float4*>(xb + 4);
        __builtin_amdgcn_sched_barrier(0);
        gload16(bS, smem0 + bLds);
        __builtin_amdgcn_sched_barrier(0);
        uint4 o;
        o.x = pkbf(ra0.x, ra0.y); o.y = pkbf(ra0.z, ra0.w);
        o.z = pkbf(ra1.x, ra1.y); o.w = pkbf(ra1.z, ra1.w);
        *reinterpret_cast<uint4*>(smem0 + wA) = o;   // compiler waits rA only
        asm volatile("s_waitcnt lgkmcnt(0)" ::: "memory");
        __builtin_amdgcn_s_barrier();
    }
    // loop invariant at iteration entry: outstanding vmem = [B(kt)]

    for (int kt = 0; kt < NKT; ++kt) {
        const int kn = (kt + 1 < NKT) ? kt + 1 : NKT - 1;  // clamp: redundant last loads
        const int koff = (kn >> 3) * 50176 + (kn & 7) * 448; // c*224*224 + ph*224
        char* bufn = smem0 + (u32)(((kt + 1) & 1) * 16384);
        char* bufc = smem0 + (u32)((kt & 1) * 16384);

        // issue-early: A(kt+1) f32 -> regs, then B(kt+1) -> LDS (order pinned)
        float4 ra0 = *reinterpret_cast<const float4*>(xb + koff);
        float4 ra1 = *reinterpret_cast<const float4*>(xb + koff + 4);
        __builtin_amdgcn_sched_barrier(0);
        gload16(bS + kn * BK, bufn + bLds);
        __builtin_amdgcn_sched_barrier(0);
        // wait only B(kt); [rA x2, B(kt+1)] stay in flight
        asm volatile("s_waitcnt vmcnt(3)" ::: "memory");
        __builtin_amdgcn_s_barrier();

        bf16x8 af[2], bfr[4];
        #pragma unroll
        for (int fm = 0; fm < 2; ++fm)
            af[fm] = *reinterpret_cast<const bf16x8*>(bufc + aOff[fm]);
        #pragma unroll
        for (int fn = 0; fn < 4; ++fn)
            bfr[fn] = *reinterpret_cast<const bf16x8*>(bufc + bOff[fn]);

        #pragma unroll
        for (int fm = 0; fm < 2; ++fm)
            #pragma unroll
            for (int fn = 0; fn < 4; ++fn)
                acc[fm][fn] = __builtin_amdgcn_mfma_f32_16x16x32_bf16(
                    af[fm], bfr[fn], acc[fm][fn], 0, 0, 0);

        // write-late: A(kt+1) -> bufn (compiler inserts vmcnt(1) for rA;
        // B(kt+1) remains in flight across the barrier)
        uint4 o;
        o.x = pkbf(ra0.x, ra0.y); o.y = pkbf(ra0.z, ra0.w);
        o.z = pkbf(ra1.x, ra1.y); o.w = pkbf(ra1.z, ra1.w);
        *reinterpret_cast<uint4*>(bufn + wA) = o;
        asm volatile("s_waitcnt lgkmcnt(0)" ::: "memory");
        __builtin_amdgcn_s_barrier();
    }

    // ---- store: bias + eps-replace, rows < 196 only ----
    const int r4 = (l >> 4) * 4;
    #pragma unroll
    for (int fm = 0; fm < 2; ++fm) {
        int mb = m0 + wm * 32 + fm * 16 + r4;
        #pragma unroll
        for (int fn = 0; fn < 4; ++fn) {
            int col = n0 + wn * 64 + fn * 16 + (l & 15);
            float bias = b_exp[e * CN + col];
            #pragma unroll
            for (int q = 0; q < 4; ++q) {
                int mrow = mb + q;
                if (mrow < NP) {
                    float vv = acc[fm][fn][q] + bias;
                    if (vv == 0.0f) vv = 2.220446049250313e-16f;
                    out[((size_t)b * NP + mrow) * CN + col] = vv;
                }
            }
        }
    }
}

extern "C" void kernel_launch(void* const* d_in, const int* in_sizes, int n_in,
                              void* d_out, int out_size, void* d_ws, size_t ws_size,
                              hipStream_t stream) {
    const float* x       = (const float*)d_in[0];
    const float* g       = (const float*)d_in[1];
    const float* noise   = (const float*)d_in[2];
    const float* w_gate  = (const float*)d_in[3];
    const float* w_noise = (const float*)d_in[4];
    const float* w_exp   = (const float*)d_in[5];
    const float* b_exp   = (const float*)d_in[6];
    float* out = (float*)d_out;

    char* ws = (char*)d_ws;
    int*   eid = (int*)ws;                    // 256 B
    float* gCl = (float*)(ws + 256);          // 2 KB
    float* gSd = (float*)(ws + 2304);         // 2 KB
    float* gNy = (float*)(ws + 4352);         // 2 KB
    u16*   wbf = (u16*)(ws + 8192);           // 8*768*768*2 = 9.4 MB

    hipLaunchKernelGGL(prep1_kernel, dim3(8 + WCONV_BLOCKS), dim3(256), 0, stream,
                       g, noise, w_gate, w_noise, w_exp, gCl, gSd, gNy, wbf);
    hipLaunchKernelGGL(gate2_kernel, dim3(1), dim3(512), 0, stream,
                       gCl, gSd, gNy, eid, out + (size_t)NB * NP * CN);
    hipLaunchKernelGGL(gemm_kernel, dim3(CN / BN * (2 * NB)), dim3(512), 0, stream,
                       x, wbf, b_exp, eid, out);
}

// Round 7
// 57.508 us; speedup vs baseline: 1.6011x; 1.0088x over previous
//
#include <hip/hip_runtime.h>
#include <math.h>

typedef unsigned short u16;
typedef unsigned int   u32;

using bf16x8 = __attribute__((ext_vector_type(8))) short;
using f32x4  = __attribute__((ext_vector_type(4))) float;

#define NB   64      // batch
#define NE   8       // experts
#define DIN  320
#define NP   196     // real patches per image
#define CK   768     // inner dim (C*P*P)
#define CN   768     // out features

#define BM 128
#define BN 128
#define BK 32        // LDS row = 64 B = 4 chunks of 16B
#define NKT (CK / BK)   // 24

#define WCONV_BLOCKS 2304   // 8*768*768 / (8*256)

__device__ __forceinline__ u16 f2bf(float f) {
    u32 u = __builtin_bit_cast(u32, f);
    u += 0x7fffu + ((u >> 16) & 1u);
    return (u16)(u >> 16);
}

// round-half-up f32->bf16 pair pack
__device__ __forceinline__ u32 pkbf(float a, float b) {
    u32 ua = (__builtin_bit_cast(u32, a) + 0x8000u) >> 16;
    u32 ub = (__builtin_bit_cast(u32, b) + 0x8000u) & 0xffff0000u;
    return ua | ub;
}

__device__ __forceinline__ void gload16(const void* g, void* l) {
    __builtin_amdgcn_global_load_lds(
        (const __attribute__((address_space(1))) void*)g,
        (__attribute__((address_space(3))) void*)l, 16, 0, 0);
}

// ---------------- prep1: gate1 (blocks 0..7) + wconv (rest) ----------------
__global__ __launch_bounds__(256) void prep1_kernel(
    const float* __restrict__ g,
    const float* __restrict__ noise,
    const float* __restrict__ w_gate,
    const float* __restrict__ w_noise,
    const float* __restrict__ w_exp,
    float* __restrict__ gCl, float* __restrict__ gSd, float* __restrict__ gNy,
    u16* __restrict__ wb)
{
    __shared__ float sW[DIN][NE + 1];    // +1 pad: breaks 8-way bank conflict
    __shared__ float sWn[DIN][NE + 1];
    const int t = threadIdx.x;
    int bid = blockIdx.x;

    if (bid < 8) {
        // gate stage 1: 8 blocks x 8 images; thread=(pair,q), q sums 80 dims
        for (int i = t; i < DIN * NE; i += 256) {
            sW[i >> 3][i & 7]  = w_gate[i];
            sWn[i >> 3][i & 7] = w_noise[i];
        }
        __syncthreads();
        const int pair = t >> 2, q = t & 3;
        const int bl = pair >> 3, e = pair & 7;
        const int b = bid * 8 + bl;
        float cl = 0.f, nz = 0.f;
        const float* gr = g + b * DIN + q * 80;
        #pragma unroll 4
        for (int j = 0; j < 80; ++j) {
            float gv = gr[j];
            cl = fmaf(gv, sW[q * 80 + j][e], cl);
            nz = fmaf(gv, sWn[q * 80 + j][e], nz);
        }
        cl += __shfl_xor(cl, 1); cl += __shfl_xor(cl, 2);
        nz += __shfl_xor(nz, 1); nz += __shfl_xor(nz, 2);
        if (q == 0) {
            int p = b * NE + e;
            // jax.nn.softplus == max(x,0)+log1p(exp(-|x|))
            float sd = fmaxf(nz, 0.f) + log1pf(expf(-fabsf(nz))) + 0.01f;
            gCl[p] = cl; gSd[p] = sd;
            gNy[p] = fmaf(noise[p], sd, cl);
        }
        return;
    }
    bid -= 8;
    // w_exp fp32 -> bf16 (8 elems/thread)
    int idx = bid * 256 + t;
    const float* src = w_exp + (size_t)idx * 8;
    float4 f0 = *reinterpret_cast<const float4*>(src);
    float4 f1 = *reinterpret_cast<const float4*>(src + 4);
    uint4 o;
    o.x = (u32)f2bf(f0.x) | ((u32)f2bf(f0.y) << 16);
    o.y = (u32)f2bf(f0.z) | ((u32)f2bf(f0.w) << 16);
    o.z = (u32)f2bf(f1.x) | ((u32)f2bf(f1.y) << 16);
    o.w = (u32)f2bf(f1.z) | ((u32)f2bf(f1.w) << 16);
    *reinterpret_cast<uint4*>(wb + (size_t)idx * 8) = o;
}

// ---------------- gate stage 2: top-2, probs, loss, eid (1 block) ----------------
__global__ __launch_bounds__(512) void gate2_kernel(
    const float* __restrict__ gCl,
    const float* __restrict__ gSd,
    const float* __restrict__ gNy,
    int* __restrict__ eid,
    float* __restrict__ loss_out)
{
    __shared__ float sNy[NB][NE];
    __shared__ float sProb[NB][NE];
    __shared__ int   sTop[NB];
    __shared__ float sImp[NE], sLoad[NE];
    const int t = threadIdx.x;            // 512 = one (b,e) pair each
    const int b = t >> 3, e = t & 7;
    float cl = gCl[t], sd = gSd[t], ny = gNy[t];
    sNy[b][e] = ny;
    __syncthreads();
    float v1 = -1e30f, v2 = -1e30f; int i1 = 0;
    #pragma unroll
    for (int k2 = 0; k2 < NE; ++k2) {
        float v = sNy[b][k2];
        if (v > v1) { v2 = v1; v1 = v; i1 = k2; }
        else if (v > v2) { v2 = v; }
    }
    if (e == 0) { sTop[b] = i1; eid[b] = i1; }
    // is_in: noisy > 2nd-largest (thr_in=v2); else threshold = largest (v1)
    float thr = (ny > v2) ? v2 : v1;
    float z = (cl - thr) / sd;
    sProb[b][e] = 0.5f * (1.0f + erff(z * 0.7071067811865476f));
    __syncthreads();
    if (t < NE) {
        float imp = 0.f, ld = 0.f;
        for (int i = 0; i < NB; ++i) {
            imp += (sTop[i] == t) ? 1.0f : 0.0f;
            ld  += sProb[i][t];
        }
        sImp[t] = imp; sLoad[t] = ld;
    }
    __syncthreads();
    if (t == 0) {
        float mi = 0.f, ml = 0.f;
        for (int k2 = 0; k2 < NE; ++k2) { mi += sImp[k2]; ml += sLoad[k2]; }
        mi *= (1.0f / NE); ml *= (1.0f / NE);
        float vi = 0.f, vl = 0.f;
        for (int k2 = 0; k2 < NE; ++k2) {
            float d1 = sImp[k2] - mi;  vi += d1 * d1;
            float d2 = sLoad[k2] - ml; vl += d2 * d2;
        }
        vi *= (1.0f / (NE - 1)); vl *= (1.0f / (NE - 1));  // ddof=1
        loss_out[0] = (vi / (mi * mi + 1e-10f) + vl / (ml * ml + 1e-10f)) * 0.01f;
    }
}

// ---------------- fused patchify+GEMM: one K-step ----------------
// iter kt: wait vmcnt(6) [drains B(kt); in flight: A(kt+1)x4 regs, B(kt+1)x2];
// barrier; issue A(kt+2)->sL regs + B(kt+2)->gload_lds(bn); compute tile kt
// from bc; ds_write A(kt+1) (sW) -> bw (compiler auto-waits its regs).
template<bool LOAD, bool WRITE, bool LAST>
__device__ __forceinline__ void kstep(
    char* sm, u32 bc, u32 bw, u32 bn, int kn,
    const float* xc0, const float* xc1, u32 aw0, u32 aw1,
    const u16* bS0, const u16* bS1, u32 bLds,
    const u32 (&aOff)[4], const u32 (&bOff)[4],
    float4 (&sL)[4], float4 (&sW)[4], f32x4 (&acc)[4][4])
{
    if constexpr (LAST) asm volatile("s_waitcnt vmcnt(0) lgkmcnt(0)" ::: "memory");
    else                asm volatile("s_waitcnt vmcnt(6) lgkmcnt(0)" ::: "memory");
    __builtin_amdgcn_s_barrier();
    __builtin_amdgcn_sched_barrier(0);
    if constexpr (LOAD) {
        const int koff = (kn >> 3) * 50176 + (kn & 7) * 448;
        sL[0] = *reinterpret_cast<const float4*>(xc0 + koff);
        sL[1] = *reinterpret_cast<const float4*>(xc0 + koff + 4);
        sL[2] = *reinterpret_cast<const float4*>(xc1 + koff);
        sL[3] = *reinterpret_cast<const float4*>(xc1 + koff + 4);
        __builtin_amdgcn_sched_barrier(0);
        gload16(bS0 + kn * BK, sm + bn + 8192 + bLds);
        gload16(bS1 + kn * BK, sm + bn + 8192 + bLds + 1024);
        __builtin_amdgcn_sched_barrier(0);
    }
    bf16x8 af[4], bfr[4];
    #pragma unroll
    for (int fm = 0; fm < 4; ++fm)
        af[fm] = *reinterpret_cast<const bf16x8*>(sm + bc + aOff[fm]);
    #pragma unroll
    for (int fn = 0; fn < 4; ++fn)
        bfr[fn] = *reinterpret_cast<const bf16x8*>(sm + bc + 8192 + bOff[fn]);
    #pragma unroll
    for (int fm = 0; fm < 4; ++fm)
        #pragma unroll
        for (int fn = 0; fn < 4; ++fn)
            acc[fm][fn] = __builtin_amdgcn_mfma_f32_16x16x32_bf16(
                af[fm], bfr[fn], acc[fm][fn], 0, 0, 0);
    if constexpr (WRITE) {
        __builtin_amdgcn_sched_barrier(0);   // keep pack+write after MFMAs
        uint4 o0, o1;
        o0.x = pkbf(sW[0].x, sW[0].y); o0.y = pkbf(sW[0].z, sW[0].w);
        o0.z = pkbf(sW[1].x, sW[1].y); o0.w = pkbf(sW[1].z, sW[1].w);
        o1.x = pkbf(sW[2].x, sW[2].y); o1.y = pkbf(sW[2].z, sW[2].w);
        o1.z = pkbf(sW[3].x, sW[3].y); o1.w = pkbf(sW[3].z, sW[3].w);
        *reinterpret_cast<uint4*>(sm + bw + aw0) = o0;
        *reinterpret_cast<uint4*>(sm + bw + aw1) = o1;
    }
}

// 768 blocks -> (image b, m-tile 0/1, n-tile 0..5); 256 thr = 4 waves (2x2),
// wave tile 64x64. A fused from x (f32->bf16 reg staging, depth-1 regs);
// B via global_load_lds depth-2; tri-buffer LDS; ONE barrier per K-step.
__global__ __launch_bounds__(256, 3) void gemm_kernel(
    const float* __restrict__ x,
    const u16* __restrict__ wb,
    const float* __restrict__ b_exp,
    const int* __restrict__ eid,
    float* __restrict__ out)
{
    __shared__ char smem[3 * 16384];   // 3 buffers: A 8KB | B 8KB each

    const int id = blockIdx.x;
    // bijective XCD swizzle: 96 consecutive virtual blocks (=8 images) per XCD
    const int v  = (id & 7) * 96 + (id >> 3);
    const int b  = v / 12;
    const int rr = v % 12;
    const int m0 = (rr / 6) * BM;
    const int n0 = (rr % 6) * BN;
    const int e  = eid[b];

    const int t  = threadIdx.x;
    const int l  = t & 63;
    const int w  = t >> 6;
    const int wm = w >> 1;
    const int wn = w & 1;
    char* sm = smem;

    // ---- B staging (gload_lds, 2 rows/thread): row rs=(w*32)+(l>>2), +16 ----
    // LDS chunk c'=l&3; pre-swizzled global chunk cg = (l&3)^(l>>4)
    const int rs = (w << 5) + (l >> 2);
    const u32 cg = (u32)((l & 3) ^ (l >> 4));
    const u16* bS0 = wb + (size_t)e * (CK * CN) + (size_t)(n0 + rs) * CK + cg * 8;
    const u16* bS1 = bS0 + (size_t)16 * CK;
    const u32 bLds = ((u32)w << 11) + ((u32)l << 4);   // w*2048 + l*16

    // ---- A staging from x: thread handles chunks {t, t+256} ----
    u32 aw0, aw1;
    const float *xc0, *xc1;
    {
        int gc = t;
        int r = gc >> 2, cpr = gc & 3, s = (r >> 2) & 3;
        int cg2 = cpr ^ s, seg = cg2 >> 1, px0 = (cg2 & 1) * 8;
        int p = m0 + r; if (p > NP - 1) p = NP - 1;   // clamped rows never stored
        xc0 = x + (size_t)b * 150528 + (p / 14 * 16 + seg) * 224 + (p % 14) * 16 + px0;
        aw0 = (u32)(r * 64 + cpr * 16);
        gc = t + 256;
        r = gc >> 2; cpr = gc & 3; s = (r >> 2) & 3;
        cg2 = cpr ^ s; seg = cg2 >> 1; px0 = (cg2 & 1) * 8;
        p = m0 + r; if (p > NP - 1) p = NP - 1;
        xc1 = x + (size_t)b * 150528 + (p / 14 * 16 + seg) * 224 + (p % 14) * 16 + px0;
        aw1 = (u32)(r * 64 + cpr * 16);
    }

    // ---- fragment read offsets (chunk swizzle c = (l>>4) ^ ((row>>2)&3)) ----
    u32 aOff[4], bOff[4];
    #pragma unroll
    for (int fm = 0; fm < 4; ++fm) {
        int row = wm * 64 + fm * 16 + (l & 15);
        aOff[fm] = (u32)(row * 64) + (((u32)(l >> 4) ^ (u32)((row >> 2) & 3)) << 4);
    }
    #pragma unroll
    for (int fn = 0; fn < 4; ++fn) {
        int row = wn * 64 + fn * 16 + (l & 15);
        bOff[fn] = (u32)(row * 64) + (((u32)(l >> 4) ^ (u32)((row >> 2) & 3)) << 4);
    }

    f32x4 acc[4][4];
    #pragma unroll
    for (int fm = 0; fm < 4; ++fm)
        #pragma unroll
        for (int fn = 0; fn < 4; ++fn)
            acc[fm][fn] = (f32x4){0.f, 0.f, 0.f, 0.f};

    float4 sA0[4], sA1[4];

    // ---- prologue: A(0)->sA0, B(0)->buf0; A(1)->sA1, B(1)->buf1;
    //      ds_write A(0)->buf0 (compiler auto-waits sA0's 4 loads) ----
    sA0[0] = *reinterpret_cast<const float4*>(xc0);
    sA0[1] = *reinterpret_cast<const float4*>(xc0 + 4);
    sA0[2] = *reinterpret_cast<const float4*>(xc1);
    sA0[3] = *reinterpret_cast<const float4*>(xc1 + 4);
    __builtin_amdgcn_sched_barrier(0);
    gload16(bS0, sm + 8192 + bLds);
    gload16(bS1, sm + 8192 + bLds + 1024);
    __builtin_amdgcn_sched_barrier(0);
    sA1[0] = *reinterpret_cast<const float4*>(xc0 + 448);
    sA1[1] = *reinterpret_cast<const float4*>(xc0 + 448 + 4);
    sA1[2] = *reinterpret_cast<const float4*>(xc1 + 448);
    sA1[3] = *reinterpret_cast<const float4*>(xc1 + 448 + 4);
    __builtin_amdgcn_sched_barrier(0);
    gload16(bS0 + BK, sm + 16384 + 8192 + bLds);
    gload16(bS1 + BK, sm + 16384 + 8192 + bLds + 1024);
    __builtin_amdgcn_sched_barrier(0);
    {
        uint4 o0, o1;
        o0.x = pkbf(sA0[0].x, sA0[0].y); o0.y = pkbf(sA0[0].z, sA0[0].w);
        o0.z = pkbf(sA0[1].x, sA0[1].y); o0.w = pkbf(sA0[1].z, sA0[1].w);
        o1.x = pkbf(sA0[2].x, sA0[2].y); o1.y = pkbf(sA0[2].z, sA0[2].w);
        o1.z = pkbf(sA0[3].x, sA0[3].y); o1.w = pkbf(sA0[3].z, sA0[3].w);
        *reinterpret_cast<uint4*>(sm + aw0) = o0;
        *reinterpret_cast<uint4*>(sm + aw1) = o1;
    }

    // ---- main loop: 11 pairs covering iters 0..21; rotate tri-buffer ----
    u32 q0 = 0, q1 = 16384, q2 = 32768;
    for (int kt = 0; kt < NKT - 2; kt += 2) {
        kstep<true,  true, false>(sm, q0, q1, q2, kt + 2, xc0, xc1, aw0, aw1,
                                  bS0, bS1, bLds, aOff, bOff, sA0, sA1, acc);
        kstep<true,  true, false>(sm, q1, q2, q0, kt + 3, xc0, xc1, aw0, aw1,
                                  bS0, bS1, bLds, aOff, bOff, sA1, sA0, acc);
        u32 tq = q0; q0 = q2; q2 = q1; q1 = tq;   // rotate by 2
    }
    // ---- tail: iter 22 (write A(23), no loads), iter 23 (vmcnt(0)) ----
    kstep<false, true, false>(sm, q0, q1, q2, 0, xc0, xc1, aw0, aw1,
                              bS0, bS1, bLds, aOff, bOff, sA0, sA1, acc);
    kstep<false, false, true>(sm, q1, q2, q0, 0, xc0, xc1, aw0, aw1,
                              bS0, bS1, bLds, aOff, bOff, sA1, sA0, acc);

    // ---- store: bias + eps-replace, rows < 196 only ----
    const int r4 = (l >> 4) * 4;
    #pragma unroll
    for (int fm = 0; fm < 4; ++fm) {
        int mb = m0 + wm * 64 + fm * 16 + r4;
        #pragma unroll
        for (int fn = 0; fn < 4; ++fn) {
            int col = n0 + wn * 64 + fn * 16 + (l & 15);
            float bias = b_exp[e * CN + col];
            #pragma unroll
            for (int q = 0; q < 4; ++q) {
                int mrow = mb + q;
                if (mrow < NP) {
                    float vv = acc[fm][fn][q] + bias;
                    if (vv == 0.0f) vv = 2.220446049250313e-16f;
                    out[((size_t)b * NP + mrow) * CN + col] = vv;
                }
            }
        }
    }
}

extern "C" void kernel_launch(void* const* d_in, const int* in_sizes, int n_in,
                              void* d_out, int out_size, void* d_ws, size_t ws_size,
                              hipStream_t stream) {
    const float* x       = (const float*)d_in[0];
    const float* g       = (const float*)d_in[1];
    const float* noise   = (const float*)d_in[2];
    const float* w_gate  = (const float*)d_in[3];
    const float* w_noise = (const float*)d_in[4];
    const float* w_exp   = (const float*)d_in[5];
    const float* b_exp   = (const float*)d_in[6];
    float* out = (float*)d_out;

    char* ws = (char*)d_ws;
    int*   eid = (int*)ws;                    // 256 B
    float* gCl = (float*)(ws + 256);          // 2 KB
    float* gSd = (float*)(ws + 2304);         // 2 KB
    float* gNy = (float*)(ws + 4352);         // 2 KB
    u16*   wbf = (u16*)(ws + 8192);           // 8*768*768*2 = 9.4 MB

    hipLaunchKernelGGL(prep1_kernel, dim3(8 + WCONV_BLOCKS), dim3(256), 0, stream,
                       g, noise, w_gate, w_noise, w_exp, gCl, gSd, gNy, wbf);
    hipLaunchKernelGGL(gate2_kernel, dim3(1), dim3(512), 0, stream,
                       gCl, gSd, gNy, eid, out + (size_t)NB * NP * CN);
    hipLaunchKernelGGL(gemm_kernel, dim3(CN / BN * (2 * NB)), dim3(256), 0, stream,
                       x, wbf, b_exp, eid, out);
}